// Round 8
// baseline (287.152 us; speedup 1.0000x reference)
//
#include <hip/hip_runtime.h>
#include <hip/hip_fp16.h>
#include <math.h>

#define N_NODES 100000
#define N_EDGES 1600000
#define EP (N_EDGES + N_NODES)   // edges incl self-loops
#define HID 64
#define NBUCK 782                                // buckets of 128 node-keys (ceil(1e5/128))
#define CAP 2816                                 // fixed ebuf window per bucket (mean 2048, +17 sigma)
#define NTILE (N_NODES / 16)                     // 6250 tiles = blocks (exact)
#define NPN 4                                    // nodes per wave (gather), even
#define SC_THREADS (N_EDGES / 4)                 // 400000 int4 edge-quads

typedef _Float16 half8_t __attribute__((ext_vector_type(8)));
typedef _Float16 half4_t __attribute__((ext_vector_type(4)));
typedef float f32x4_t __attribute__((ext_vector_type(4)));
typedef unsigned long long u64;

// ================= fp8 e4m3 helpers (storage-only quantization) =================

__device__ __forceinline__ float fp8_to_f32_1(unsigned b) {
    unsigned s = b >> 7, e = (b >> 3) & 15, m = b & 7;
    float mag = (e == 0) ? (float)m * 0.001953125f
                         : __uint_as_float(((e + 120u) << 23) | (m << 20));
    return s ? -mag : mag;
}

__device__ __forceinline__ unsigned f32_to_fp8_1(float f) {
    unsigned sb = (__float_as_uint(f) >> 31) << 7;
    float a = fabsf(f);
    if (a > 448.f) a = 448.f;
    if (a < 0.001953125f * 0.5f) return sb;               // -> 0
    if (a < 0.015625f) {                                  // denormal range < 2^-6
        int q = (int)(a * 512.f + 0.5f);
        if (q > 7) return sb | (1u << 3);                 // rounds up to 2^-6
        return sb | (unsigned)q;
    }
    unsigned bits = __float_as_uint(a) + (1u << 19);      // round mantissa to 3 bits
    int e = (int)((bits >> 23) & 255) - 127;
    unsigned m = (bits >> 20) & 7;
    int ee = e + 7;
    if (ee > 15) { ee = 15; m = 6; }                      // clamp at 448, avoid NaN
    return sb | ((unsigned)ee << 3) | m;
}

// accumulate 4 fp8 (packed in u32, row-consecutive cols) into float4
__device__ __forceinline__ void addp8(float4& a, unsigned w, bool pred) {
    if (pred) {
#if __has_builtin(__builtin_amdgcn_cvt_pk_f32_fp8)
        auto lo = __builtin_amdgcn_cvt_pk_f32_fp8((int)w, false);
        auto hi = __builtin_amdgcn_cvt_pk_f32_fp8((int)w, true);
        a.x += lo[0]; a.y += lo[1]; a.z += hi[0]; a.w += hi[1];
#else
        a.x += fp8_to_f32_1(w & 255);
        a.y += fp8_to_f32_1((w >> 8) & 255);
        a.z += fp8_to_f32_1((w >> 16) & 255);
        a.w += fp8_to_f32_1(w >> 24);
#endif
    }
}

__device__ __forceinline__ unsigned pack_fp8x4(float a, float b, float c, float d) {
#if __has_builtin(__builtin_amdgcn_cvt_pk_fp8_f32)
    int v = 0;
    v = __builtin_amdgcn_cvt_pk_fp8_f32(a, b, v, false);
    v = __builtin_amdgcn_cvt_pk_fp8_f32(c, d, v, true);
    return (unsigned)v;
#else
    return f32_to_fp8_1(a) | (f32_to_fp8_1(b) << 8) |
           (f32_to_fp8_1(c) << 16) | (f32_to_fp8_1(d) << 24);
#endif
}

// ================= CSR build v9: single-pass scatter (line-padded cursors) =================
// gcur: one cursor per 64 B line (stride 16 u32) -> no TCC hot-line serialization.

__global__ void init_kernel(int* __restrict__ gcur, int* __restrict__ csr) {
    int t = threadIdx.x;
    for (int b = t; b < NBUCK; b += 512) gcur[b * 16] = b * CAP;
    if (t < 64) csr[EP + t] = 0;
}

__global__ __launch_bounds__(1024)
void scatter_kernel(const int* __restrict__ src, const int* __restrict__ dst,
                    int* __restrict__ gcur, unsigned* __restrict__ ebuf) {
    int t = blockIdx.x * 1024 + threadIdx.x;
    if (t >= SC_THREADS) return;
    int4 d = ((const int4*)dst)[t];
    int4 s = ((const int4*)src)[t];
    int p0 = atomicAdd(&gcur[(d.x >> 7) * 16], 1);
    ebuf[p0] = ((unsigned)(d.x & 127) << 17) | (unsigned)s.x;   // src < 2^17
    int p1 = atomicAdd(&gcur[(d.y >> 7) * 16], 1);
    ebuf[p1] = ((unsigned)(d.y & 127) << 17) | (unsigned)s.y;
    int p2 = atomicAdd(&gcur[(d.z >> 7) * 16], 1);
    ebuf[p2] = ((unsigned)(d.z & 127) << 17) | (unsigned)s.z;
    int p3 = atomicAdd(&gcur[(d.w >> 7) * 16], 1);
    ebuf[p3] = ((unsigned)(d.w & 127) << 17) | (unsigned)s.w;
}

__global__ __launch_bounds__(256)
void rankfill_kernel(const unsigned* __restrict__ ebuf, const int* __restrict__ gcur,
                     int* __restrict__ rowptr, int* __restrict__ csr,
                     float* __restrict__ dinv,
                     const float* __restrict__ x, float4* __restrict__ xd) {
    __shared__ unsigned stash[CAP];       // raw bucket entries
    __shared__ int out[CAP + 128];        // reordered bucket (edges + self-loops)
    __shared__ int cnt[128];              // per-node degree (pass A)
    __shared__ int cnt2[128];             // per-node rank counter (pass B)
    __shared__ int rpl8[128];             // node region start, bucket-relative
    __shared__ int wsum[2];
    __shared__ int sR0;
    const int tid = threadIdx.x, b = blockIdx.x;
    if (tid < 128) { cnt[tid] = 0; cnt2[tid] = 0; }
    if (tid == 0) sR0 = 0;
    __syncthreads();

    int acc = 0;
    for (int i = tid; i < b; i += 256) acc += gcur[i * 16] - i * CAP + 128;
    if (acc) atomicAdd(&sR0, acc);

    const int E0 = b * CAP;
    const int RL = gcur[b * 16] - E0;     // bucket edge count (<= CAP)
    for (int off = tid; off < RL; off += 256) {
        unsigned v = ebuf[E0 + off];
        stash[off] = v;
        atomicAdd(&cnt[(v >> 17) & 0x7F], 1);
    }
    __syncthreads();
    const int R0 = sR0;

    const int lane = tid & 63, w = tid >> 6;
    int xcnt = (tid < 128) ? cnt[tid] : 0;
    int inc = xcnt;
#pragma unroll
    for (int off = 1; off < 64; off <<= 1) {
        int y = __shfl_up(inc, off, 64);
        if (lane >= off) inc += y;
    }
    if (lane == 63 && w < 2) wsum[w] = inc;
    __syncthreads();
    if (tid < 128) {
        int base = (w == 1) ? wsum[0] : 0;
        int rel = tid + base + inc - xcnt;
        rpl8[tid] = rel;
        const int n = b * 128 + tid;
        if (n < N_NODES) {
            rowptr[n] = R0 + rel;
            float di = rsqrtf((float)(xcnt + 1));
            dinv[n] = di;
            out[rel + xcnt] = n;              // self-loop at end of node's list
            xd[n] = make_float4(x[n * 3 + 0] * di, x[n * 3 + 1] * di, x[n * 3 + 2] * di, 0.f);
        }
    }
    if (b == NBUCK - 1 && tid == 0) rowptr[N_NODES] = EP;
    __syncthreads();

    for (int off = tid; off < RL; off += 256) {
        unsigned v = stash[off];
        int key = (v >> 17) & 0x7F;
        int r = atomicAdd(&cnt2[key], 1);
        out[rpl8[key] + r] = (int)(v & 0x1FFFFu);
    }
    __syncthreads();

    const int nreal = min(128, N_NODES - b * 128);
    const int lim = RL + nreal;
    for (int i = tid; i < lim; i += 256) csr[R0 + i] = out[i];
}

// ================= fused layer: fp8 gather (R5 schedule, direct csr indices) =================

__device__ __forceinline__ void bfly_store_lds(float4 acc, const float4 b4, float di,
                                               int g, int p, int l, _Float16* __restrict__ tl) {
    acc.x += __shfl_xor(acc.x, 16, 64);
    acc.y += __shfl_xor(acc.y, 16, 64);
    acc.z += __shfl_xor(acc.z, 16, 64);
    acc.w += __shfl_xor(acc.w, 16, 64);
    acc.x += __shfl_xor(acc.x, 32, 64);
    acc.y += __shfl_xor(acc.y, 32, 64);
    acc.z += __shfl_xor(acc.z, 32, 64);
    acc.w += __shfl_xor(acc.w, 32, 64);
    if (g == 0) {
        half4_t hv;
        hv[0] = (_Float16)fmaxf(fmaf(di, acc.x, b4.x), 0.f);
        hv[1] = (_Float16)fmaxf(fmaf(di, acc.y, b4.y), 0.f);
        hv[2] = (_Float16)fmaxf(fmaf(di, acc.z, b4.z), 0.f);
        hv[3] = (_Float16)fmaxf(fmaf(di, acc.w, b4.w), 0.f);
        *(half4_t*)(tl + l * 72 + p * 4) = hv;
    }
}

// gf: fp8 [N][64] = [N] rows of 16 u32. Lane p owns cols p*4..p*4+3.
// Index path: group-g lanes load csr[beg + 4k + g] directly (16 lanes share the
// address -> 1 broadcast request, L1-hot) instead of ds_bpermute distribution.
// Masked slots select row 0 (cache-hot, no wasted random fetch).
__device__ __forceinline__ void gather_phase(const unsigned* __restrict__ gfq,
                                             const int* __restrict__ rowptr,
                                             const int* __restrict__ csr,
                                             const float* __restrict__ dinv,
                                             const float* __restrict__ bias,
                                             int n0, int lane, int wid,
                                             _Float16* __restrict__ tl) {
    const int g = lane >> 4, p = lane & 15;
    const int nw = n0 + wid * NPN;
    int rp = rowptr[nw + min(lane, NPN)];
    const float4 b4 = ((const float4*)bias)[p];
    int begv[NPN], cntv[NPN];
    int end_prev = __shfl(rp, 0, 64);
#pragma unroll
    for (int i = 0; i < NPN; ++i) {
        int end = __shfl(rp, i + 1, 64);
        begv[i] = end_prev;
        cntv[i] = end - end_prev;
        end_prev = end;
    }
#pragma unroll
    for (int ii = 0; ii < NPN; ii += 2) {
        const int la = wid * NPN + ii, lb = la + 1;
        const int ca = cntv[ii], cb = cntv[ii + 1];
        const int ba = begv[ii], bb = begv[ii + 1];
        int sa0 = (g      < ca) ? csr[ba + g]      : 0;
        int sb0 = (g      < cb) ? csr[bb + g]      : 0;
        int sa1 = (g + 4  < ca) ? csr[ba + g + 4]  : 0;
        int sb1 = (g + 4  < cb) ? csr[bb + g + 4]  : 0;
        int sa2 = (g + 8  < ca) ? csr[ba + g + 8]  : 0;
        int sb2 = (g + 8  < cb) ? csr[bb + g + 8]  : 0;
        int sa3 = (g + 12 < ca) ? csr[ba + g + 12] : 0;
        int sb3 = (g + 12 < cb) ? csr[bb + g + 12] : 0;
        unsigned ua0 = gfq[(size_t)sa0 * 16 + p], ub0 = gfq[(size_t)sb0 * 16 + p];
        unsigned ua1 = gfq[(size_t)sa1 * 16 + p], ub1 = gfq[(size_t)sb1 * 16 + p];
        unsigned ua2 = gfq[(size_t)sa2 * 16 + p], ub2 = gfq[(size_t)sb2 * 16 + p];
        unsigned ua3 = gfq[(size_t)sa3 * 16 + p], ub3 = gfq[(size_t)sb3 * 16 + p];
        float4 accA = make_float4(0.f, 0.f, 0.f, 0.f);
        float4 accB = make_float4(0.f, 0.f, 0.f, 0.f);
        addp8(accA, ua0, g + 0 < ca);  addp8(accB, ub0, g + 0 < cb);
        addp8(accA, ua1, g + 4 < ca);  addp8(accB, ub1, g + 4 < cb);
        addp8(accA, ua2, g + 8 < ca);  addp8(accB, ub2, g + 8 < cb);
        addp8(accA, ua3, g + 12 < ca); addp8(accB, ub3, g + 12 < cb);
        if (ca > 16) {
#pragma unroll
            for (int k = 4; k < 8; ++k) {
                int e = g + 4 * k;
                int s = (e < ca) ? csr[ba + e] : 0;
                addp8(accA, gfq[(size_t)s * 16 + p], e < ca);
            }
            if (ca > 32) {
                for (int e = 32 + g; e < ca; e += 4)
                    addp8(accA, gfq[(size_t)csr[ba + e] * 16 + p], true);
            }
        }
        if (cb > 16) {
#pragma unroll
            for (int k = 4; k < 8; ++k) {
                int e = g + 4 * k;
                int s = (e < cb) ? csr[bb + e] : 0;
                addp8(accB, gfq[(size_t)s * 16 + p], e < cb);
            }
            if (cb > 32) {
                for (int e = 32 + g; e < cb; e += 4)
                    addp8(accB, gfq[(size_t)csr[bb + e] * 16 + p], true);
            }
        }
        bfly_store_lds(accA, b4, dinv[n0 + la], g, p, la, tl);
        bfly_store_lds(accB, b4, dinv[n0 + lb], g, p, lb, tl);
    }
}

// MFMA @W, scale by dinv, emit fp8 rows
__device__ __forceinline__ void mfma_fp8_store(const float* __restrict__ W,
                                               const float* __restrict__ dinv, int n0,
                                               int lane, int wid, int tid,
                                               _Float16* __restrict__ tile,
                                               _Float16* __restrict__ tile2,
                                               unsigned* __restrict__ gf_out) {
    const int kg = lane >> 4, n = lane & 15;
    half8_t B0, B1;
#pragma unroll
    for (int j = 0; j < 8; ++j) {
        B0[j] = (_Float16)W[(kg * 8 + j) * HID + wid * 16 + n];
        B1[j] = (_Float16)W[(32 + kg * 8 + j) * HID + wid * 16 + n];
    }
    half8_t A0 = *(const half8_t*)(tile + n * 72 + kg * 8);
    half8_t A1 = *(const half8_t*)(tile + n * 72 + 32 + kg * 8);
    f32x4_t c = {0.f, 0.f, 0.f, 0.f};
    c = __builtin_amdgcn_mfma_f32_16x16x32_f16(A0, B0, c, 0, 0, 0);
    c = __builtin_amdgcn_mfma_f32_16x16x32_f16(A1, B1, c, 0, 0, 0);
    const int q = lane >> 4;
#pragma unroll
    for (int r = 0; r < 4; ++r)
        tile2[(q * 4 + r) * 72 + wid * 16 + n] = (_Float16)(c[r] * dinv[n0 + q * 4 + r]);
    __syncthreads();
    const int row = tid >> 4, seg = tid & 15;
    uint2 v = *(const uint2*)(tile2 + row * 72 + seg * 4);
    __half2 h0 = *(__half2*)&v.x, h1 = *(__half2*)&v.y;
    float2 f0 = __half22float2(h0), f1 = __half22float2(h1);
    gf_out[(size_t)(n0 + row) * 16 + seg] = pack_fp8x4(f0.x, f0.y, f1.x, f1.y);
}

// ================= fused layer 1: 3-dim fp32 gather (linearity) -> fp8 out =================

__global__ __launch_bounds__(256, 8)
void fused_layer1_kernel(const float4* __restrict__ xd, const int* __restrict__ rowptr,
                         const int* __restrict__ csr, const float* __restrict__ dinv,
                         const float* __restrict__ b1, const float* __restrict__ W1,
                         const float* __restrict__ W2, unsigned* __restrict__ gf_out) {
    __shared__ __align__(16) _Float16 tile[16 * 72];
    __shared__ __align__(16) _Float16 tile2[16 * 72];
    const int tid = threadIdx.x;
    const int lane = tid & 63, wid = tid >> 6;
    const int n0 = blockIdx.x * 16;

    const int j = lane >> 4, p0 = lane & 15;
    const int l = wid * 4 + j;            // tile-local node 0..15
    const int node = n0 + l;
    const int beg = rowptr[node], end = rowptr[node + 1];
    float a0 = 0.f, a1 = 0.f, a2 = 0.f;
    for (int e = beg + p0; e < end; e += 16) {
        float4 v = xd[csr[e]];
        a0 += v.x; a1 += v.y; a2 += v.z;
    }
#pragma unroll
    for (int off = 1; off < 16; off <<= 1) {
        a0 += __shfl_xor(a0, off, 64);
        a1 += __shfl_xor(a1, off, 64);
        a2 += __shfl_xor(a2, off, 64);
    }
    const float dd = dinv[node];
    const float4 w0 = ((const float4*)W1)[p0];
    const float4 w1 = ((const float4*)(W1 + HID))[p0];
    const float4 w2 = ((const float4*)(W1 + 2 * HID))[p0];
    const float4 bb = ((const float4*)b1)[p0];
    half4_t hv;
    hv[0] = (_Float16)fmaxf(fmaf(dd, a0 * w0.x + a1 * w1.x + a2 * w2.x, bb.x), 0.f);
    hv[1] = (_Float16)fmaxf(fmaf(dd, a0 * w0.y + a1 * w1.y + a2 * w2.y, bb.y), 0.f);
    hv[2] = (_Float16)fmaxf(fmaf(dd, a0 * w0.z + a1 * w1.z + a2 * w2.z, bb.z), 0.f);
    hv[3] = (_Float16)fmaxf(fmaf(dd, a0 * w0.w + a1 * w1.w + a2 * w2.w, bb.w), 0.f);
    *(half4_t*)(tile + l * 72 + p0 * 4) = hv;
    __syncthreads();

    mfma_fp8_store(W2, dinv, n0, lane, wid, tid, tile, tile2, gf_out);
}

__global__ __launch_bounds__(256, 8)
void fused_layer_kernel(const unsigned* __restrict__ gf_in, const int* __restrict__ rowptr,
                        const int* __restrict__ csr, const float* __restrict__ dinv,
                        const float* __restrict__ bias, const float* __restrict__ W,
                        unsigned* __restrict__ gf_out) {
    __shared__ __align__(16) _Float16 tile[16 * 72];
    __shared__ __align__(16) _Float16 tile2[16 * 72];
    const int tid = threadIdx.x;
    const int lane = tid & 63, wid = tid >> 6;
    const int n0 = blockIdx.x * 16;

    gather_phase(gf_in, rowptr, csr, dinv, bias, n0, lane, wid, tile);
    __syncthreads();

    mfma_fp8_store(W, dinv, n0, lane, wid, tid, tile, tile2, gf_out);
}

// ================= fused final: fp8 gather -> MFMA(Wm1) + head + sigmoid =================

__global__ __launch_bounds__(256, 8)
void fused_final_kernel(const unsigned* __restrict__ gf_in, const int* __restrict__ rowptr,
                        const int* __restrict__ csr, const float* __restrict__ dinv,
                        const float* __restrict__ b3, const float* __restrict__ Wm1,
                        const float* __restrict__ bm1, const float* __restrict__ Wm2,
                        const float* __restrict__ bm2, float* __restrict__ out) {
    __shared__ __align__(16) _Float16 tile[16 * 72];
    __shared__ float redbuf[4][16];
    const int tid = threadIdx.x;
    const int lane = tid & 63, wid = tid >> 6;
    const int n0 = blockIdx.x * 16;

    gather_phase(gf_in, rowptr, csr, dinv, b3, n0, lane, wid, tile);
    __syncthreads();

    const int kg = lane >> 4, n = lane & 15;
    half8_t B0, B1;
#pragma unroll
    for (int j = 0; j < 8; ++j) {
        B0[j] = (_Float16)Wm1[(kg * 8 + j) * HID + wid * 16 + n];
        B1[j] = (_Float16)Wm1[(32 + kg * 8 + j) * HID + wid * 16 + n];
    }
    half8_t A0 = *(const half8_t*)(tile + n * 72 + kg * 8);
    half8_t A1 = *(const half8_t*)(tile + n * 72 + 32 + kg * 8);
    f32x4_t c = {0.f, 0.f, 0.f, 0.f};
    c = __builtin_amdgcn_mfma_f32_16x16x32_f16(A0, B0, c, 0, 0, 0);
    c = __builtin_amdgcn_mfma_f32_16x16x32_f16(A1, B1, c, 0, 0, 0);

    const float bm1c = bm1[wid * 16 + n];
    const float wm2c = Wm2[wid * 16 + n];
    float part[4];
#pragma unroll
    for (int r = 0; r < 4; ++r) part[r] = fmaxf(c[r] + bm1c, 0.0f) * wm2c;
#pragma unroll
    for (int off = 1; off < 16; off <<= 1)
#pragma unroll
        for (int r = 0; r < 4; ++r) part[r] += __shfl_xor(part[r], off, 64);
    const int q = lane >> 4;
    if (n == 0) {
#pragma unroll
        for (int r = 0; r < 4; ++r) redbuf[wid][q * 4 + r] = part[r];
    }
    __syncthreads();
    if (tid < 16) {
        float s = redbuf[0][tid] + redbuf[1][tid] + redbuf[2][tid] + redbuf[3][tid];
        out[n0 + tid] = 1.0f / (1.0f + expf(-(s + bm2[0])));
    }
}

// ---------------- launch ----------------

extern "C" void kernel_launch(void* const* d_in, const int* in_sizes, int n_in,
                              void* d_out, int out_size, void* d_ws, size_t ws_size,
                              hipStream_t stream) {
    const float* x   = (const float*)d_in[0];
    const int*   ei  = (const int*)d_in[1];
    const float* W1  = (const float*)d_in[2];
    const float* b1  = (const float*)d_in[3];
    const float* W2  = (const float*)d_in[4];
    const float* b2  = (const float*)d_in[5];
    const float* W3  = (const float*)d_in[6];
    const float* b3  = (const float*)d_in[7];
    const float* Wm1 = (const float*)d_in[8];
    const float* bm1 = (const float*)d_in[9];
    const float* Wm2 = (const float*)d_in[10];
    const float* bm2 = (const float*)d_in[11];
    float* out = (float*)d_out;

    const int* src = ei;
    const int* dst = ei + N_EDGES;

    char* ws = (char*)d_ws;
    size_t off = 0;
    auto alloc = [&](size_t bytes) { size_t o = off; off = (off + bytes + 255) & ~(size_t)255; return (void*)(ws + o); };
    int*      rowptr = (int*)alloc(4ll * (N_NODES + 1));
    int*      gcur   = (int*)alloc(4ll * NBUCK * 16);      // line-padded cursors (64 B each)
    int*      csr    = (int*)alloc(4ll * (EP + 64));       // +64 pad (zeros)
    float*    dinv   = (float*)alloc(4ll * N_NODES);
    float4*   xd     = (float4*)alloc(16ll * N_NODES);     // dinv*x packed, 1.6 MB (L2-resident)
    unsigned* gfA    = (unsigned*)alloc(4ll * N_NODES * 16);   // fp8 [N][64] = 6.4 MB
    unsigned* gfB    = (unsigned*)alloc(4ll * N_NODES * 16);
    unsigned* ebuf   = (unsigned*)alloc(4ll * (size_t)NBUCK * CAP);
    (void)ws_size;

    // --- CSR build v9: single-pass scatter ---
    init_kernel<<<1, 512, 0, stream>>>(gcur, csr);
    scatter_kernel<<<(SC_THREADS + 1023) / 1024, 1024, 0, stream>>>(src, dst, gcur, ebuf);
    rankfill_kernel<<<NBUCK, 256, 0, stream>>>(ebuf, gcur, rowptr, csr, dinv, x, xd);

    // --- layers (gf buffers fp8 e4m3) ---
    fused_layer1_kernel<<<NTILE, 256, 0, stream>>>(xd, rowptr, csr, dinv, b1, W1, W2, gfB);
    fused_layer_kernel<<<NTILE, 256, 0, stream>>>(gfB, rowptr, csr, dinv, b2, W3, gfA);
    fused_final_kernel<<<NTILE, 256, 0, stream>>>(gfA, rowptr, csr, dinv, b3, Wm1, bm1, Wm2, bm2, out);
}

// Round 9
// 190.056 us; speedup vs baseline: 1.5109x; 1.5109x over previous
//
#include <hip/hip_runtime.h>
#include <hip/hip_fp16.h>
#include <math.h>

#define N_NODES 100000
#define N_EDGES 1600000
#define EP (N_EDGES + N_NODES)   // edges incl self-loops
#define HID 64
#define NCHUNK 250                               // scatter chunks (>= 1 block per CU)
#define CE (N_EDGES / NCHUNK)                    // 6400 edges per chunk (exact, /4 ok)
#define NBUCK 782                                // buckets of 128 node-keys (ceil(1e5/128))
#define CAP 2816                                 // fixed ebuf window per bucket (mean 2048, +17 sigma)
#define NTILE (N_NODES / 16)                     // 6250 tiles = blocks (exact)
#define NPN 4                                    // nodes per wave (gather), even

typedef _Float16 half8_t __attribute__((ext_vector_type(8)));
typedef _Float16 half4_t __attribute__((ext_vector_type(4)));
typedef float f32x4_t __attribute__((ext_vector_type(4)));
typedef unsigned long long u64;

// ================= fp8 e4m3 helpers (storage-only quantization) =================

__device__ __forceinline__ float fp8_to_f32_1(unsigned b) {
    unsigned s = b >> 7, e = (b >> 3) & 15, m = b & 7;
    float mag = (e == 0) ? (float)m * 0.001953125f
                         : __uint_as_float(((e + 120u) << 23) | (m << 20));
    return s ? -mag : mag;
}

__device__ __forceinline__ unsigned f32_to_fp8_1(float f) {
    unsigned sb = (__float_as_uint(f) >> 31) << 7;
    float a = fabsf(f);
    if (a > 448.f) a = 448.f;
    if (a < 0.001953125f * 0.5f) return sb;               // -> 0
    if (a < 0.015625f) {                                  // denormal range < 2^-6
        int q = (int)(a * 512.f + 0.5f);
        if (q > 7) return sb | (1u << 3);                 // rounds up to 2^-6
        return sb | (unsigned)q;
    }
    unsigned bits = __float_as_uint(a) + (1u << 19);      // round mantissa to 3 bits
    int e = (int)((bits >> 23) & 255) - 127;
    unsigned m = (bits >> 20) & 7;
    int ee = e + 7;
    if (ee > 15) { ee = 15; m = 6; }                      // clamp at 448, avoid NaN
    return sb | ((unsigned)ee << 3) | m;
}

// accumulate 4 fp8 (packed in u32, row-consecutive cols) into float4
__device__ __forceinline__ void addp8(float4& a, unsigned w, bool pred) {
    if (pred) {
#if __has_builtin(__builtin_amdgcn_cvt_pk_f32_fp8)
        auto lo = __builtin_amdgcn_cvt_pk_f32_fp8((int)w, false);
        auto hi = __builtin_amdgcn_cvt_pk_f32_fp8((int)w, true);
        a.x += lo[0]; a.y += lo[1]; a.z += hi[0]; a.w += hi[1];
#else
        a.x += fp8_to_f32_1(w & 255);
        a.y += fp8_to_f32_1((w >> 8) & 255);
        a.z += fp8_to_f32_1((w >> 16) & 255);
        a.w += fp8_to_f32_1(w >> 24);
#endif
    }
}

__device__ __forceinline__ unsigned pack_fp8x4(float a, float b, float c, float d) {
#if __has_builtin(__builtin_amdgcn_cvt_pk_fp8_f32)
    int v = 0;
    v = __builtin_amdgcn_cvt_pk_fp8_f32(a, b, v, false);
    v = __builtin_amdgcn_cvt_pk_fp8_f32(c, d, v, true);
    return (unsigned)v;
#else
    return f32_to_fp8_1(a) | (f32_to_fp8_1(b) << 8) |
           (f32_to_fp8_1(c) << 16) | (f32_to_fp8_1(d) << 24);
#endif
}

// ================= bucketed CSR build v8 (R5-proven, two-pass scatter) =================

__global__ void init_kernel(int* __restrict__ gcur, int* __restrict__ csr) {
    int t = threadIdx.x;
    for (int b = t; b < NBUCK; b += 512) gcur[b] = b * CAP;
    if (t < 64) csr[EP + t] = 0;
}

__global__ __launch_bounds__(1024)
void scatter_kernel(const int* __restrict__ src, const int* __restrict__ dst,
                    int* __restrict__ gcur, unsigned* __restrict__ ebuf) {
    __shared__ int hist[NBUCK];
    __shared__ int cur[NBUCK];
    const int tid = threadIdx.x, c = blockIdx.x;
    for (int b = tid; b < NBUCK; b += 1024) hist[b] = 0;
    __syncthreads();
    const int4* d4p = (const int4*)(dst + c * CE);
    const int4* s4p = (const int4*)(src + c * CE);
    // each thread owns <= 2 quads; cache them in regs across the two passes
    const int t0 = tid, t1 = tid + 1024;
    const bool v1 = t1 < CE / 4;                  // t0 always < 1600
    int4 d0 = d4p[t0], s0 = s4p[t0];
    int4 d1, s1;
    if (v1) { d1 = d4p[t1]; s1 = s4p[t1]; }
    atomicAdd(&hist[d0.x >> 7], 1);
    atomicAdd(&hist[d0.y >> 7], 1);
    atomicAdd(&hist[d0.z >> 7], 1);
    atomicAdd(&hist[d0.w >> 7], 1);
    if (v1) {
        atomicAdd(&hist[d1.x >> 7], 1);
        atomicAdd(&hist[d1.y >> 7], 1);
        atomicAdd(&hist[d1.z >> 7], 1);
        atomicAdd(&hist[d1.w >> 7], 1);
    }
    __syncthreads();
    for (int b = tid; b < NBUCK; b += 1024)
        cur[b] = hist[b] ? atomicAdd(&gcur[b], hist[b]) : 0;
    __syncthreads();
    {
        int p0 = atomicAdd(&cur[d0.x >> 7], 1);
        ebuf[p0] = ((unsigned)(d0.x & 127) << 17) | (unsigned)s0.x;   // src < 2^17
        int p1 = atomicAdd(&cur[d0.y >> 7], 1);
        ebuf[p1] = ((unsigned)(d0.y & 127) << 17) | (unsigned)s0.y;
        int p2 = atomicAdd(&cur[d0.z >> 7], 1);
        ebuf[p2] = ((unsigned)(d0.z & 127) << 17) | (unsigned)s0.z;
        int p3 = atomicAdd(&cur[d0.w >> 7], 1);
        ebuf[p3] = ((unsigned)(d0.w & 127) << 17) | (unsigned)s0.w;
    }
    if (v1) {
        int p0 = atomicAdd(&cur[d1.x >> 7], 1);
        ebuf[p0] = ((unsigned)(d1.x & 127) << 17) | (unsigned)s1.x;
        int p1 = atomicAdd(&cur[d1.y >> 7], 1);
        ebuf[p1] = ((unsigned)(d1.y & 127) << 17) | (unsigned)s1.y;
        int p2 = atomicAdd(&cur[d1.z >> 7], 1);
        ebuf[p2] = ((unsigned)(d1.z & 127) << 17) | (unsigned)s1.z;
        int p3 = atomicAdd(&cur[d1.w >> 7], 1);
        ebuf[p3] = ((unsigned)(d1.w & 127) << 17) | (unsigned)s1.w;
    }
}

__global__ __launch_bounds__(256)
void rankfill_kernel(const unsigned* __restrict__ ebuf, const int* __restrict__ gcur,
                     int* __restrict__ rowptr, int* __restrict__ csr,
                     float* __restrict__ dinv,
                     const float* __restrict__ x, float4* __restrict__ xd) {
    __shared__ unsigned stash[CAP];       // raw bucket entries
    __shared__ int out[CAP + 128];        // reordered bucket (edges + self-loops)
    __shared__ int cnt[128];              // per-node degree (pass A)
    __shared__ int cnt2[128];             // per-node rank counter (pass B)
    __shared__ int rpl8[128];             // node region start, bucket-relative
    __shared__ int wsum[2];
    __shared__ int sR0;
    const int tid = threadIdx.x, b = blockIdx.x;
    if (tid < 128) { cnt[tid] = 0; cnt2[tid] = 0; }
    if (tid == 0) sR0 = 0;
    __syncthreads();

    int acc = 0;
    for (int i = tid; i < b; i += 256) acc += gcur[i] - i * CAP + 128;
    if (acc) atomicAdd(&sR0, acc);

    const int E0 = b * CAP;
    const int RL = gcur[b] - E0;          // bucket edge count (<= CAP)
    for (int off = tid; off < RL; off += 256) {
        unsigned v = ebuf[E0 + off];
        stash[off] = v;
        atomicAdd(&cnt[(v >> 17) & 0x7F], 1);
    }
    __syncthreads();
    const int R0 = sR0;

    const int lane = tid & 63, w = tid >> 6;
    int xcnt = (tid < 128) ? cnt[tid] : 0;
    int inc = xcnt;
#pragma unroll
    for (int off = 1; off < 64; off <<= 1) {
        int y = __shfl_up(inc, off, 64);
        if (lane >= off) inc += y;
    }
    if (lane == 63 && w < 2) wsum[w] = inc;
    __syncthreads();
    if (tid < 128) {
        int base = (w == 1) ? wsum[0] : 0;
        int rel = tid + base + inc - xcnt;
        rpl8[tid] = rel;
        const int n = b * 128 + tid;
        if (n < N_NODES) {
            rowptr[n] = R0 + rel;
            float di = rsqrtf((float)(xcnt + 1));
            dinv[n] = di;
            out[rel + xcnt] = n;              // self-loop at end of node's list
            xd[n] = make_float4(x[n * 3 + 0] * di, x[n * 3 + 1] * di, x[n * 3 + 2] * di, 0.f);
        }
    }
    if (b == NBUCK - 1 && tid == 0) rowptr[N_NODES] = EP;
    __syncthreads();

    for (int off = tid; off < RL; off += 256) {
        unsigned v = stash[off];
        int key = (v >> 17) & 0x7F;
        int r = atomicAdd(&cnt2[key], 1);
        out[rpl8[key] + r] = (int)(v & 0x1FFFFu);
    }
    __syncthreads();

    const int nreal = min(128, N_NODES - b * 128);
    const int lim = RL + nreal;
    for (int i = tid; i < lim; i += 256) csr[R0 + i] = out[i];
}

// ================= fused layer: fp8 gather (R5-proven shfl schedule) =================

__device__ __forceinline__ void bfly_store_lds(float4 acc, const float4 b4, float di,
                                               int g, int p, int l, _Float16* __restrict__ tl) {
    acc.x += __shfl_xor(acc.x, 16, 64);
    acc.y += __shfl_xor(acc.y, 16, 64);
    acc.z += __shfl_xor(acc.z, 16, 64);
    acc.w += __shfl_xor(acc.w, 16, 64);
    acc.x += __shfl_xor(acc.x, 32, 64);
    acc.y += __shfl_xor(acc.y, 32, 64);
    acc.z += __shfl_xor(acc.z, 32, 64);
    acc.w += __shfl_xor(acc.w, 32, 64);
    if (g == 0) {
        half4_t hv;
        hv[0] = (_Float16)fmaxf(fmaf(di, acc.x, b4.x), 0.f);
        hv[1] = (_Float16)fmaxf(fmaf(di, acc.y, b4.y), 0.f);
        hv[2] = (_Float16)fmaxf(fmaf(di, acc.z, b4.z), 0.f);
        hv[3] = (_Float16)fmaxf(fmaf(di, acc.w, b4.w), 0.f);
        *(half4_t*)(tl + l * 72 + p * 4) = hv;
    }
}

// gf: fp8 [N][64] = [N] rows of 16 u32. Lane p owns cols p*4..p*4+3.
__device__ __forceinline__ void gather_phase(const unsigned* __restrict__ gfq,
                                             const int* __restrict__ rowptr,
                                             const int* __restrict__ csr,
                                             const float* __restrict__ dinv,
                                             const float* __restrict__ bias,
                                             int n0, int lane, int wid,
                                             _Float16* __restrict__ tl) {
    const int g = lane >> 4, p = lane & 15;
    const int nw = n0 + wid * NPN;
    int rp = rowptr[nw + min(lane, NPN)];
    const float4 b4 = ((const float4*)bias)[p];
    int begv[NPN], cntv[NPN], idxv[NPN];
    int end_prev = __shfl(rp, 0, 64);
#pragma unroll
    for (int i = 0; i < NPN; ++i) {
        int end = __shfl(rp, i + 1, 64);
        begv[i] = end_prev;
        cntv[i] = end - end_prev;
        end_prev = end;
        idxv[i] = (lane < cntv[i]) ? csr[begv[i] + lane] : 0;
    }
#pragma unroll
    for (int ii = 0; ii < NPN; ii += 2) {
        const int la = wid * NPN + ii, lb = la + 1;
        const int ca = cntv[ii], cb = cntv[ii + 1];
        const int ba = begv[ii], bb = begv[ii + 1];
        const int iva = idxv[ii], ivb = idxv[ii + 1];
        int sa0 = __shfl(iva, g, 64),      sb0 = __shfl(ivb, g, 64);
        int sa1 = __shfl(iva, g + 4, 64),  sb1 = __shfl(ivb, g + 4, 64);
        int sa2 = __shfl(iva, g + 8, 64),  sb2 = __shfl(ivb, g + 8, 64);
        int sa3 = __shfl(iva, g + 12, 64), sb3 = __shfl(ivb, g + 12, 64);
        unsigned ua0 = gfq[(size_t)sa0 * 16 + p], ub0 = gfq[(size_t)sb0 * 16 + p];
        unsigned ua1 = gfq[(size_t)sa1 * 16 + p], ub1 = gfq[(size_t)sb1 * 16 + p];
        unsigned ua2 = gfq[(size_t)sa2 * 16 + p], ub2 = gfq[(size_t)sb2 * 16 + p];
        unsigned ua3 = gfq[(size_t)sa3 * 16 + p], ub3 = gfq[(size_t)sb3 * 16 + p];
        float4 accA = make_float4(0.f, 0.f, 0.f, 0.f);
        float4 accB = make_float4(0.f, 0.f, 0.f, 0.f);
        addp8(accA, ua0, g + 0 < ca);  addp8(accB, ub0, g + 0 < cb);
        addp8(accA, ua1, g + 4 < ca);  addp8(accB, ub1, g + 4 < cb);
        addp8(accA, ua2, g + 8 < ca);  addp8(accB, ub2, g + 8 < cb);
        addp8(accA, ua3, g + 12 < ca); addp8(accB, ub3, g + 12 < cb);
        if (ca > 16) {
#pragma unroll
            for (int k = 4; k < 8; ++k) {
                int e = g + 4 * k;
                int s = __shfl(iva, e, 64);
                addp8(accA, gfq[(size_t)s * 16 + p], e < ca);
            }
            if (ca > 32) {
                for (int e = 32 + g; e < ca; e += 4) {
                    int s = (e < 64) ? __shfl(iva, e, 64) : csr[ba + e];
                    addp8(accA, gfq[(size_t)s * 16 + p], true);
                }
            }
        }
        if (cb > 16) {
#pragma unroll
            for (int k = 4; k < 8; ++k) {
                int e = g + 4 * k;
                int s = __shfl(ivb, e, 64);
                addp8(accB, gfq[(size_t)s * 16 + p], e < cb);
            }
            if (cb > 32) {
                for (int e = 32 + g; e < cb; e += 4) {
                    int s = (e < 64) ? __shfl(ivb, e, 64) : csr[bb + e];
                    addp8(accB, gfq[(size_t)s * 16 + p], true);
                }
            }
        }
        bfly_store_lds(accA, b4, dinv[n0 + la], g, p, la, tl);
        bfly_store_lds(accB, b4, dinv[n0 + lb], g, p, lb, tl);
    }
}

// MFMA @W, scale by dinv, emit fp8 rows
__device__ __forceinline__ void mfma_fp8_store(const float* __restrict__ W,
                                               const float* __restrict__ dinv, int n0,
                                               int lane, int wid, int tid,
                                               _Float16* __restrict__ tile,
                                               _Float16* __restrict__ tile2,
                                               unsigned* __restrict__ gf_out) {
    const int kg = lane >> 4, n = lane & 15;
    half8_t B0, B1;
#pragma unroll
    for (int j = 0; j < 8; ++j) {
        B0[j] = (_Float16)W[(kg * 8 + j) * HID + wid * 16 + n];
        B1[j] = (_Float16)W[(32 + kg * 8 + j) * HID + wid * 16 + n];
    }
    half8_t A0 = *(const half8_t*)(tile + n * 72 + kg * 8);
    half8_t A1 = *(const half8_t*)(tile + n * 72 + 32 + kg * 8);
    f32x4_t c = {0.f, 0.f, 0.f, 0.f};
    c = __builtin_amdgcn_mfma_f32_16x16x32_f16(A0, B0, c, 0, 0, 0);
    c = __builtin_amdgcn_mfma_f32_16x16x32_f16(A1, B1, c, 0, 0, 0);
    const int q = lane >> 4;
#pragma unroll
    for (int r = 0; r < 4; ++r)
        tile2[(q * 4 + r) * 72 + wid * 16 + n] = (_Float16)(c[r] * dinv[n0 + q * 4 + r]);
    __syncthreads();
    const int row = tid >> 4, seg = tid & 15;
    uint2 v = *(const uint2*)(tile2 + row * 72 + seg * 4);
    __half2 h0 = *(__half2*)&v.x, h1 = *(__half2*)&v.y;
    float2 f0 = __half22float2(h0), f1 = __half22float2(h1);
    gf_out[(size_t)(n0 + row) * 16 + seg] = pack_fp8x4(f0.x, f0.y, f1.x, f1.y);
}

// ================= fused layer 1: 3-dim fp32 gather (linearity) -> fp8 out =================

__global__ __launch_bounds__(256, 8)
void fused_layer1_kernel(const float4* __restrict__ xd, const int* __restrict__ rowptr,
                         const int* __restrict__ csr, const float* __restrict__ dinv,
                         const float* __restrict__ b1, const float* __restrict__ W1,
                         const float* __restrict__ W2, unsigned* __restrict__ gf_out) {
    __shared__ __align__(16) _Float16 tile[16 * 72];
    __shared__ __align__(16) _Float16 tile2[16 * 72];
    const int tid = threadIdx.x;
    const int lane = tid & 63, wid = tid >> 6;
    const int n0 = blockIdx.x * 16;

    const int j = lane >> 4, p0 = lane & 15;
    const int l = wid * 4 + j;            // tile-local node 0..15
    const int node = n0 + l;
    const int beg = rowptr[node], end = rowptr[node + 1];
    float a0 = 0.f, a1 = 0.f, a2 = 0.f;
    for (int e = beg + p0; e < end; e += 16) {
        float4 v = xd[csr[e]];
        a0 += v.x; a1 += v.y; a2 += v.z;
    }
#pragma unroll
    for (int off = 1; off < 16; off <<= 1) {
        a0 += __shfl_xor(a0, off, 64);
        a1 += __shfl_xor(a1, off, 64);
        a2 += __shfl_xor(a2, off, 64);
    }
    const float dd = dinv[node];
    const float4 w0 = ((const float4*)W1)[p0];
    const float4 w1 = ((const float4*)(W1 + HID))[p0];
    const float4 w2 = ((const float4*)(W1 + 2 * HID))[p0];
    const float4 bb = ((const float4*)b1)[p0];
    half4_t hv;
    hv[0] = (_Float16)fmaxf(fmaf(dd, a0 * w0.x + a1 * w1.x + a2 * w2.x, bb.x), 0.f);
    hv[1] = (_Float16)fmaxf(fmaf(dd, a0 * w0.y + a1 * w1.y + a2 * w2.y, bb.y), 0.f);
    hv[2] = (_Float16)fmaxf(fmaf(dd, a0 * w0.z + a1 * w1.z + a2 * w2.z, bb.z), 0.f);
    hv[3] = (_Float16)fmaxf(fmaf(dd, a0 * w0.w + a1 * w1.w + a2 * w2.w, bb.w), 0.f);
    *(half4_t*)(tile + l * 72 + p0 * 4) = hv;
    __syncthreads();

    mfma_fp8_store(W2, dinv, n0, lane, wid, tid, tile, tile2, gf_out);
}

__global__ __launch_bounds__(256, 8)
void fused_layer_kernel(const unsigned* __restrict__ gf_in, const int* __restrict__ rowptr,
                        const int* __restrict__ csr, const float* __restrict__ dinv,
                        const float* __restrict__ bias, const float* __restrict__ W,
                        unsigned* __restrict__ gf_out) {
    __shared__ __align__(16) _Float16 tile[16 * 72];
    __shared__ __align__(16) _Float16 tile2[16 * 72];
    const int tid = threadIdx.x;
    const int lane = tid & 63, wid = tid >> 6;
    const int n0 = blockIdx.x * 16;

    gather_phase(gf_in, rowptr, csr, dinv, bias, n0, lane, wid, tile);
    __syncthreads();

    mfma_fp8_store(W, dinv, n0, lane, wid, tid, tile, tile2, gf_out);
}

// ================= fused final: fp8 gather -> MFMA(Wm1) + head + sigmoid =================

__global__ __launch_bounds__(256, 8)
void fused_final_kernel(const unsigned* __restrict__ gf_in, const int* __restrict__ rowptr,
                        const int* __restrict__ csr, const float* __restrict__ dinv,
                        const float* __restrict__ b3, const float* __restrict__ Wm1,
                        const float* __restrict__ bm1, const float* __restrict__ Wm2,
                        const float* __restrict__ bm2, float* __restrict__ out) {
    __shared__ __align__(16) _Float16 tile[16 * 72];
    __shared__ float redbuf[4][16];
    const int tid = threadIdx.x;
    const int lane = tid & 63, wid = tid >> 6;
    const int n0 = blockIdx.x * 16;

    gather_phase(gf_in, rowptr, csr, dinv, b3, n0, lane, wid, tile);
    __syncthreads();

    const int kg = lane >> 4, n = lane & 15;
    half8_t B0, B1;
#pragma unroll
    for (int j = 0; j < 8; ++j) {
        B0[j] = (_Float16)Wm1[(kg * 8 + j) * HID + wid * 16 + n];
        B1[j] = (_Float16)Wm1[(32 + kg * 8 + j) * HID + wid * 16 + n];
    }
    half8_t A0 = *(const half8_t*)(tile + n * 72 + kg * 8);
    half8_t A1 = *(const half8_t*)(tile + n * 72 + 32 + kg * 8);
    f32x4_t c = {0.f, 0.f, 0.f, 0.f};
    c = __builtin_amdgcn_mfma_f32_16x16x32_f16(A0, B0, c, 0, 0, 0);
    c = __builtin_amdgcn_mfma_f32_16x16x32_f16(A1, B1, c, 0, 0, 0);

    const float bm1c = bm1[wid * 16 + n];
    const float wm2c = Wm2[wid * 16 + n];
    float part[4];
#pragma unroll
    for (int r = 0; r < 4; ++r) part[r] = fmaxf(c[r] + bm1c, 0.0f) * wm2c;
#pragma unroll
    for (int off = 1; off < 16; off <<= 1)
#pragma unroll
        for (int r = 0; r < 4; ++r) part[r] += __shfl_xor(part[r], off, 64);
    const int q = lane >> 4;
    if (n == 0) {
#pragma unroll
        for (int r = 0; r < 4; ++r) redbuf[wid][q * 4 + r] = part[r];
    }
    __syncthreads();
    if (tid < 16) {
        float s = redbuf[0][tid] + redbuf[1][tid] + redbuf[2][tid] + redbuf[3][tid];
        out[n0 + tid] = 1.0f / (1.0f + expf(-(s + bm2[0])));
    }
}

// ---------------- launch ----------------

extern "C" void kernel_launch(void* const* d_in, const int* in_sizes, int n_in,
                              void* d_out, int out_size, void* d_ws, size_t ws_size,
                              hipStream_t stream) {
    const float* x   = (const float*)d_in[0];
    const int*   ei  = (const int*)d_in[1];
    const float* W1  = (const float*)d_in[2];
    const float* b1  = (const float*)d_in[3];
    const float* W2  = (const float*)d_in[4];
    const float* b2  = (const float*)d_in[5];
    const float* W3  = (const float*)d_in[6];
    const float* b3  = (const float*)d_in[7];
    const float* Wm1 = (const float*)d_in[8];
    const float* bm1 = (const float*)d_in[9];
    const float* Wm2 = (const float*)d_in[10];
    const float* bm2 = (const float*)d_in[11];
    float* out = (float*)d_out;

    const int* src = ei;
    const int* dst = ei + N_EDGES;

    char* ws = (char*)d_ws;
    size_t off = 0;
    auto alloc = [&](size_t bytes) { size_t o = off; off = (off + bytes + 255) & ~(size_t)255; return (void*)(ws + o); };
    int*      rowptr = (int*)alloc(4ll * (N_NODES + 1));
    int*      gcur   = (int*)alloc(4ll * NBUCK);
    int*      csr    = (int*)alloc(4ll * (EP + 64));       // +64 pad (zeros)
    float*    dinv   = (float*)alloc(4ll * N_NODES);
    float4*   xd     = (float4*)alloc(16ll * N_NODES);     // dinv*x packed, 1.6 MB (L2-resident)
    unsigned* gfA    = (unsigned*)alloc(4ll * N_NODES * 16);   // fp8 [N][64] = 6.4 MB
    unsigned* gfB    = (unsigned*)alloc(4ll * N_NODES * 16);
    unsigned* ebuf   = (unsigned*)alloc(4ll * (size_t)NBUCK * CAP);
    (void)ws_size;

    // --- CSR build v8 (two-pass scatter, R5-proven) ---
    init_kernel<<<1, 512, 0, stream>>>(gcur, csr);
    scatter_kernel<<<NCHUNK, 1024, 0, stream>>>(src, dst, gcur, ebuf);
    rankfill_kernel<<<NBUCK, 256, 0, stream>>>(ebuf, gcur, rowptr, csr, dinv, x, xd);

    // --- layers (gf buffers fp8 e4m3) ---
    fused_layer1_kernel<<<NTILE, 256, 0, stream>>>(xd, rowptr, csr, dinv, b1, W1, W2, gfB);
    fused_layer_kernel<<<NTILE, 256, 0, stream>>>(gfB, rowptr, csr, dinv, b2, W3, gfA);
    fused_final_kernel<<<NTILE, 256, 0, stream>>>(gfA, rowptr, csr, dinv, b3, Wm1, bm1, Wm2, bm2, out);
}